// Round 1
// baseline (3687.976 us; speedup 1.0000x reference)
//
#include <hip/hip_runtime.h>
#include <math.h>

#define B_ 32
#define L_ 64
#define T_ 65      // 1 + L
#define LS_ 100
#define H_ 512
#define E_ 512
#define F_ 64
#define V_ 32000
#define SOS_ 2
#define EPS_ 1e-6f

__device__ __forceinline__ float sigmoidf_(float x) { return 1.0f / (1.0f + expf(-x)); }

// ---------------------------------------------------------------------------
// Build X: rows r = t*B + b of (T*B, E). t==0 -> embedding[SOS], else
// input_embeddings[b, t-1, :]
// ---------------------------------------------------------------------------
__global__ void build_X(const float* __restrict__ emb,
                        const float* __restrict__ inp_emb,
                        float* __restrict__ X) {
    int idx = blockIdx.x * blockDim.x + threadIdx.x;
    if (idx >= T_ * B_ * E_) return;
    int e = idx % E_;
    int r = idx / E_;
    int t = r / B_, b = r % B_;
    float v;
    if (t == 0) v = emb[(size_t)SOS_ * E_ + e];
    else        v = inp_emb[((size_t)b * L_ + (t - 1)) * E_ + e];
    X[idx] = v;
}

__global__ void init_state(const float* __restrict__ h0, const float* __restrict__ c0,
                           float* __restrict__ h_all, float* __restrict__ c_all) {
    int idx = blockIdx.x * blockDim.x + threadIdx.x;
    if (idx < B_ * H_) { h_all[idx] = h0[idx]; c_all[idx] = c0[idx]; }
}

// ---------------------------------------------------------------------------
// Generic f32 register-tiled GEMM: C = act(A[M,K](lda) @ B[K,N] + bias)
// OUTMODE 0: C[r*N+n]; OUTMODE 1: emit layout out[(b*T + t)*V + n], r = t*B+b
// MASK: rows with finished(t,b) write 0.
// ---------------------------------------------------------------------------
template <int BM, int BN, int BK, int TM, int TN, bool TANH, bool MASK, int OUTMODE>
__global__ void gemm_f32(const float* __restrict__ A, const float* __restrict__ Bm,
                         const float* __restrict__ bias, float* __restrict__ C,
                         int M, int N, int K, int lda, const int* __restrict__ lens) {
    __shared__ float As[BK][BM + 1];
    __shared__ float Bs[BK][BN + 1];
    int bm = blockIdx.y * BM;
    int bn = blockIdx.x * BN;
    int tid = threadIdx.x;  // 256 threads
    const int TX = BN / TN; // threads along n
    int tn = (tid % TX) * TN;
    int tm = (tid / TX) * TM;

    float acc[TM][TN];
#pragma unroll
    for (int i = 0; i < TM; i++)
#pragma unroll
        for (int j = 0; j < TN; j++) acc[i][j] = 0.f;

    for (int k0 = 0; k0 < K; k0 += BK) {
        for (int idx = tid; idx < BM * BK; idx += 256) {
            int r = idx / BK, c = idx % BK;
            int gr = bm + r, gc = k0 + c;
            As[c][r] = (gr < M) ? A[(size_t)gr * lda + gc] : 0.f;
        }
        for (int idx = tid; idx < BK * BN; idx += 256) {
            int r = idx / BN, c = idx % BN;
            int gr = k0 + r, gc = bn + c;
            Bs[r][c] = (gc < N) ? Bm[(size_t)gr * N + gc] : 0.f;
        }
        __syncthreads();
#pragma unroll
        for (int kk = 0; kk < BK; kk++) {
            float a[TM], b[TN];
#pragma unroll
            for (int i = 0; i < TM; i++) a[i] = As[kk][tm + i];
#pragma unroll
            for (int j = 0; j < TN; j++) b[j] = Bs[kk][tn + j];
#pragma unroll
            for (int i = 0; i < TM; i++)
#pragma unroll
                for (int j = 0; j < TN; j++) acc[i][j] += a[i] * b[j];
        }
        __syncthreads();
    }

#pragma unroll
    for (int i = 0; i < TM; i++) {
        int gr = bm + tm + i;
        if (gr >= M) continue;
        bool fin = false;
        int t = gr / B_, bb = gr % B_;
        if (MASK) fin = (t > 0) && ((t - 1) >= lens[bb]);
#pragma unroll
        for (int j = 0; j < TN; j++) {
            int gc = bn + tn + j;
            if (gc >= N) continue;
            float v = acc[i][j] + bias[gc];
            if (TANH) v = tanhf(v);
            if (MASK && fin) v = 0.f;
            size_t oidx;
            if (OUTMODE == 1) oidx = ((size_t)bb * T_ + t) * V_ + gc;
            else              oidx = (size_t)gr * N + gc;
            C[oidx] = v;
        }
    }
}

// ---------------------------------------------------------------------------
// Sequential LSTM step t: z = Zx[t*B+b] + h_prev @ lstm_W[E:, :]; gates;
// writes h_all[t+1], c_all[t+1], and o_t into ao_concat cols [512,1024)
// grid: 256 blocks (32 b * 8 j-blocks of 64), 256 threads
// ---------------------------------------------------------------------------
__global__ void lstm_step(const float* __restrict__ Zx, const float* __restrict__ lstm_W,
                          const int* __restrict__ lens,
                          float* __restrict__ h_all, float* __restrict__ c_all,
                          float* __restrict__ ao_concat, int t) {
    int b = blockIdx.x >> 3;
    int j0 = (blockIdx.x & 7) * 64;
    const float* h_prev = h_all + (size_t)t * B_ * H_ + (size_t)b * H_;
    const float* c_prev = c_all + (size_t)t * B_ * H_ + (size_t)b * H_;
    __shared__ float hs[H_];
    __shared__ float zs[4][64];
    int tid = threadIdx.x;
    for (int k = tid; k < H_; k += 256) hs[k] = h_prev[k];
    __syncthreads();
    int g = tid >> 6;
    int jj = tid & 63;
    int col = g * H_ + j0 + jj;
    float acc = Zx[((size_t)t * B_ + b) * (4 * H_) + col];
    const float* Wcol = lstm_W + (size_t)E_ * (4 * H_) + col;  // rows E..E+H-1
#pragma unroll 8
    for (int k = 0; k < H_; k++) acc += hs[k] * Wcol[(size_t)k * (4 * H_)];
    zs[g][jj] = acc;
    __syncthreads();
    if (tid < 64) {
        int j = j0 + tid;
        float zi = zs[0][tid], zj = zs[1][tid], zf = zs[2][tid], zo = zs[3][tid];
        float cp = c_prev[j];
        float c = sigmoidf_(zf + 1.0f) * cp + sigmoidf_(zi) * tanhf(zj);
        float h = sigmoidf_(zo) * tanhf(c);
        bool fin = (t > 0) && ((t - 1) >= lens[b]);
        float o_t = fin ? 0.f : h;
        float hn = fin ? h_prev[j] : h;
        float cn = fin ? cp : c;
        h_all[(size_t)(t + 1) * B_ * H_ + (size_t)b * H_ + j] = hn;
        c_all[(size_t)(t + 1) * B_ * H_ + (size_t)b * H_ + j] = cn;
        ao_concat[((size_t)t * B_ + b) * 1024 + 512 + j] = o_t;
    }
}

// ---------------------------------------------------------------------------
// Attention per (t,b): scores vs phi_hs/phi_fds, two softmaxes, combine,
// renormalize, context -> ao_concat cols [0,512)
// grid: 2080 blocks, 256 threads (4 waves)
// ---------------------------------------------------------------------------
__global__ void attention_kernel(const float* __restrict__ phi_hs,
                                 const float* __restrict__ phi_fds,
                                 const float* __restrict__ gamma,
                                 const float* __restrict__ alpha,
                                 const float* __restrict__ enc,
                                 float* __restrict__ ao_concat) {
    int r = blockIdx.x;
    int b = r % B_;
    int tid = threadIdx.x;
    __shared__ float gs[H_], asd[H_];
    __shared__ float sh[LS_], sf[LS_];
    for (int k = tid; k < H_; k += 256) {
        gs[k] = gamma[(size_t)r * H_ + k];
        asd[k] = alpha[(size_t)r * H_ + k];
    }
    __syncthreads();
    int wave = tid >> 6, lane = tid & 63;
    for (int l = wave; l < LS_; l += 4) {
        const float* ph = phi_hs + ((size_t)b * LS_ + l) * H_;
        const float* pf = phi_fds + ((size_t)b * LS_ + l) * H_;
        float s1 = 0.f, s2 = 0.f;
        for (int k = lane; k < H_; k += 64) { s1 += ph[k] * gs[k]; s2 += pf[k] * asd[k]; }
#pragma unroll
        for (int off = 32; off; off >>= 1) {
            s1 += __shfl_down(s1, off);
            s2 += __shfl_down(s2, off);
        }
        if (lane == 0) { sh[l] = s1; sf[l] = s2; }
    }
    __syncthreads();
    if (tid == 0) {
        float m1 = -1e30f, m2 = -1e30f;
        for (int l = 0; l < LS_; l++) { m1 = fmaxf(m1, sh[l]); m2 = fmaxf(m2, sf[l]); }
        float s1 = 0.f, s2 = 0.f;
        for (int l = 0; l < LS_; l++) {
            float e1 = expf(sh[l] - m1); sh[l] = e1; s1 += e1;
            float e2 = expf(sf[l] - m2); sf[l] = e2; s2 += e2;
        }
        float r1 = 1.f / (EPS_ + s1), r2 = 1.f / (EPS_ + s2);
        float s3 = 0.f;
        for (int l = 0; l < LS_; l++) { float w = (sh[l] * r1) * (sf[l] * r2); sh[l] = w; s3 += w; }
        float r3 = 1.f / (EPS_ + s3);
        for (int l = 0; l < LS_; l++) sh[l] *= r3;
    }
    __syncthreads();
    for (int h = tid; h < H_; h += 256) {
        float acc = 0.f;
        const float* eb = enc + (size_t)b * LS_ * H_ + h;
        for (int l = 0; l < LS_; l++) acc += sh[l] * eb[(size_t)l * H_];
        ao_concat[(size_t)r * 1024 + h] = acc;
    }
}

__global__ void write_final(const float* __restrict__ h_all, const float* __restrict__ c_all,
                            float* __restrict__ out) {
    int idx = blockIdx.x * blockDim.x + threadIdx.x;
    if (idx < B_ * H_) {
        size_t base = (size_t)B_ * T_ * V_;
        out[base + idx] = h_all[(size_t)T_ * B_ * H_ + idx];
        out[base + B_ * H_ + idx] = c_all[(size_t)T_ * B_ * H_ + idx];
    }
}

extern "C" void kernel_launch(void* const* d_in, const int* in_sizes, int n_in,
                              void* d_out, int out_size, void* d_ws, size_t ws_size,
                              hipStream_t stream) {
    const float* h0   = (const float*)d_in[0];
    const float* c0   = (const float*)d_in[1];
    const float* inp_emb = (const float*)d_in[2];
    const float* enc  = (const float*)d_in[3];
    const float* fld  = (const float*)d_in[4];
    const float* emb  = (const float*)d_in[5];
    const float* lstm_W = (const float*)d_in[6];
    const float* lstm_b = (const float*)d_in[7];
    const float* Wh = (const float*)d_in[8];
    const float* bh = (const float*)d_in[9];
    const float* Ws = (const float*)d_in[10];
    const float* bs = (const float*)d_in[11];
    const float* Wr = (const float*)d_in[12];
    const float* br = (const float*)d_in[13];
    const float* Wf = (const float*)d_in[14];
    const float* bf = (const float*)d_in[15];
    const float* Wo = (const float*)d_in[16];
    const float* bo = (const float*)d_in[17];
    const float* out_W = (const float*)d_in[18];
    const float* out_b = (const float*)d_in[19];
    const int*   lens  = (const int*)d_in[20];
    float* out = (float*)d_out;

    float* ws = (float*)d_ws;
    float* X       = ws; ws += (size_t)T_ * B_ * E_;        // 2080x512
    float* Zx      = ws; ws += (size_t)T_ * B_ * 4 * H_;    // 2080x2048
    float* phi_hs  = ws; ws += (size_t)B_ * LS_ * H_;       // 3200x512
    float* phi_fds = ws; ws += (size_t)B_ * LS_ * H_;       // 3200x512
    float* h_all   = ws; ws += (size_t)(T_ + 1) * B_ * H_;  // 66x32x512
    float* c_all   = ws; ws += (size_t)(T_ + 1) * B_ * H_;
    float* ao      = ws; ws += (size_t)T_ * B_ * 1024;      // 2080x1024 [context|o_t]
    float* gamma   = ws; ws += (size_t)T_ * B_ * H_;
    float* alpha   = ws; ws += (size_t)T_ * B_ * H_;
    float* att     = ws; ws += (size_t)T_ * B_ * H_;

    build_X<<<(T_ * B_ * E_ + 255) / 256, 256, 0, stream>>>(emb, inp_emb, X);
    init_state<<<(B_ * H_ + 255) / 256, 256, 0, stream>>>(h0, c0, h_all, c_all);

    // Zx = X @ lstm_W[:E,:] + lstm_b   (2080 x 2048 x 512)
    {
        dim3 g(2048 / 64, (T_ * B_ + 63) / 64);
        gemm_f32<64, 64, 16, 4, 4, false, false, 0><<<g, 256, 0, stream>>>(
            X, lstm_W, lstm_b, Zx, T_ * B_, 2048, 512, 512, nullptr);
    }
    // phi_hs = tanh(enc @ Wh + bh)   (3200 x 512 x 512)
    {
        dim3 g(512 / 64, 3200 / 64);
        gemm_f32<64, 64, 16, 4, 4, true, false, 0><<<g, 256, 0, stream>>>(
            enc, Wh, bh, phi_hs, B_ * LS_, 512, 512, 512, nullptr);
    }
    // phi_fds = tanh(fld @ Wf + bf)  (3200 x 512 x 64)
    {
        dim3 g(512 / 64, 3200 / 64);
        gemm_f32<64, 64, 16, 4, 4, true, false, 0><<<g, 256, 0, stream>>>(
            fld, Wf, bf, phi_fds, B_ * LS_, 512, 64, 64, nullptr);
    }
    // sequential LSTM chain
    for (int t = 0; t < T_; t++) {
        lstm_step<<<256, 256, 0, stream>>>(Zx, lstm_W, lens, h_all, c_all, ao, t);
    }
    // gamma = tanh(o_t @ Ws + bs); alpha = tanh(o_t @ Wr + br)
    {
        dim3 g(512 / 64, (T_ * B_ + 63) / 64);
        gemm_f32<64, 64, 16, 4, 4, true, false, 0><<<g, 256, 0, stream>>>(
            ao + 512, Ws, bs, gamma, T_ * B_, 512, 512, 1024, nullptr);
        gemm_f32<64, 64, 16, 4, 4, true, false, 0><<<g, 256, 0, stream>>>(
            ao + 512, Wr, br, alpha, T_ * B_, 512, 512, 1024, nullptr);
    }
    attention_kernel<<<T_ * B_, 256, 0, stream>>>(phi_hs, phi_fds, gamma, alpha, enc, ao);
    // att = tanh([context|o_t] @ Wo + bo), masked
    {
        dim3 g(512 / 64, (T_ * B_ + 63) / 64);
        gemm_f32<64, 64, 16, 4, 4, true, true, 0><<<g, 256, 0, stream>>>(
            ao, Wo, bo, att, T_ * B_, 512, 1024, 1024, lens);
    }
    // logits = att @ out_W + out_b, masked, scattered to emit layout
    {
        dim3 g(V_ / 64, (T_ * B_ + 63) / 64);
        gemm_f32<64, 64, 16, 4, 4, false, true, 1><<<g, 256, 0, stream>>>(
            att, out_W, out_b, out, T_ * B_, V_, 512, 512, lens);
    }
    write_final<<<(B_ * H_ + 255) / 256, 256, 0, stream>>>(h_all, c_all, out);
}

// Round 2
// 1968.319 us; speedup vs baseline: 1.8737x; 1.8737x over previous
//
#include <hip/hip_runtime.h>
#include <math.h>

#define B_ 32
#define L_ 64
#define T_ 65      // 1 + L
#define LS_ 100
#define H_ 512
#define E_ 512
#define F_ 64
#define V_ 32000
#define SOS_ 2
#define EPS_ 1e-6f

typedef __attribute__((ext_vector_type(8))) short short8;
typedef __attribute__((ext_vector_type(4))) float f32x4;

__device__ __forceinline__ float sigmoidf_(float x) { return 1.0f / (1.0f + expf(-x)); }

__device__ __forceinline__ unsigned short f2bf(float f) {
    union { float f; unsigned int u; } v; v.f = f;
    unsigned int r = v.u + 0x7fffu + ((v.u >> 16) & 1u);  // RNE
    return (unsigned short)(r >> 16);
}

__device__ __forceinline__ void gload_lds16(const void* g, void* l) {
    __builtin_amdgcn_global_load_lds(
        (const __attribute__((address_space(1))) unsigned int*)g,
        (__attribute__((address_space(3))) unsigned int*)l, 16, 0, 0);
}

// ---------------------------------------------------------------------------
__global__ void build_X(const float* __restrict__ emb,
                        const float* __restrict__ inp_emb,
                        float* __restrict__ X) {
    int idx = blockIdx.x * blockDim.x + threadIdx.x;
    if (idx >= T_ * B_ * E_) return;
    int e = idx % E_;
    int r = idx / E_;
    int t = r / B_, b = r % B_;
    float v;
    if (t == 0) v = emb[(size_t)SOS_ * E_ + e];
    else        v = inp_emb[((size_t)b * L_ + (t - 1)) * E_ + e];
    X[idx] = v;
}

__global__ void init_state(const float* __restrict__ h0, const float* __restrict__ c0,
                           float* __restrict__ h_all, float* __restrict__ c_all) {
    int idx = blockIdx.x * blockDim.x + threadIdx.x;
    if (idx < B_ * H_) { h_all[idx] = h0[idx]; c_all[idx] = c0[idx]; }
}

// ---------------------------------------------------------------------------
// Tiled transposes. dst[c][r] = src[r][c], src is R x C row-major.
// ---------------------------------------------------------------------------
__global__ void transpose_f32(const float* __restrict__ src, float* __restrict__ dst,
                              int R, int C) {
    __shared__ float tl[32][33];
    int r0 = blockIdx.y * 32, c0 = blockIdx.x * 32;
    int cx = threadIdx.x & 31, g = threadIdx.x >> 5;  // g in [0,8)
#pragma unroll
    for (int i = 0; i < 4; i++) {
        int ry = g * 4 + i;
        tl[ry][cx] = src[(size_t)(r0 + ry) * C + c0 + cx];
    }
    __syncthreads();
#pragma unroll
    for (int i = 0; i < 4; i++) {
        int cy = g * 4 + i;
        dst[(size_t)(c0 + cy) * R + r0 + cx] = tl[cx][cy];
    }
}

__global__ void transpose_f32_to_bf16(const float* __restrict__ src,
                                      unsigned short* __restrict__ dst, int R, int C) {
    __shared__ float tl[32][33];
    int r0 = blockIdx.y * 32, c0 = blockIdx.x * 32;
    int cx = threadIdx.x & 31, g = threadIdx.x >> 5;
#pragma unroll
    for (int i = 0; i < 4; i++) {
        int ry = g * 4 + i;
        tl[ry][cx] = src[(size_t)(r0 + ry) * C + c0 + cx];
    }
    __syncthreads();
#pragma unroll
    for (int i = 0; i < 4; i++) {
        int cy = g * 4 + i;
        dst[(size_t)(c0 + cy) * R + r0 + cx] = f2bf(tl[cx][cy]);
    }
}

// ---------------------------------------------------------------------------
// Generic f32 register-tiled GEMM (kept for the small/medium GEMMs).
// OUTBF16: write C as bf16 (ushort).
// ---------------------------------------------------------------------------
template <int BM, int BN, int BK, int TM, int TN, bool TANH, bool MASK, bool OUTBF16>
__global__ void gemm_f32(const float* __restrict__ A, const float* __restrict__ Bm,
                         const float* __restrict__ bias, void* __restrict__ Cout,
                         int M, int N, int K, int lda, const int* __restrict__ lens) {
    __shared__ float As[BK][BM + 1];
    __shared__ float Bs[BK][BN + 1];
    int bm = blockIdx.y * BM;
    int bn = blockIdx.x * BN;
    int tid = threadIdx.x;
    const int TX = BN / TN;
    int tn = (tid % TX) * TN;
    int tm = (tid / TX) * TM;

    float acc[TM][TN];
#pragma unroll
    for (int i = 0; i < TM; i++)
#pragma unroll
        for (int j = 0; j < TN; j++) acc[i][j] = 0.f;

    for (int k0 = 0; k0 < K; k0 += BK) {
        for (int idx = tid; idx < BM * BK; idx += 256) {
            int r = idx / BK, c = idx % BK;
            int gr = bm + r, gc = k0 + c;
            As[c][r] = (gr < M) ? A[(size_t)gr * lda + gc] : 0.f;
        }
        for (int idx = tid; idx < BK * BN; idx += 256) {
            int r = idx / BN, c = idx % BN;
            Bs[r][c] = Bm[(size_t)(k0 + r) * N + bn + c];
        }
        __syncthreads();
#pragma unroll
        for (int kk = 0; kk < BK; kk++) {
            float a[TM], b[TN];
#pragma unroll
            for (int i = 0; i < TM; i++) a[i] = As[kk][tm + i];
#pragma unroll
            for (int j = 0; j < TN; j++) b[j] = Bs[kk][tn + j];
#pragma unroll
            for (int i = 0; i < TM; i++)
#pragma unroll
                for (int j = 0; j < TN; j++) acc[i][j] += a[i] * b[j];
        }
        __syncthreads();
    }

#pragma unroll
    for (int i = 0; i < TM; i++) {
        int gr = bm + tm + i;
        if (gr >= M) continue;
        bool fin = false;
        if (MASK) {
            int t = gr >> 5, bb = gr & 31;
            fin = (t > 0) && ((t - 1) >= lens[bb]);
        }
#pragma unroll
        for (int j = 0; j < TN; j++) {
            int gc = bn + tn + j;
            float v = acc[i][j] + bias[gc];
            if (TANH) v = tanhf(v);
            if (MASK && fin) v = 0.f;
            size_t oidx = (size_t)gr * N + gc;
            if (OUTBF16) ((unsigned short*)Cout)[oidx] = f2bf(v);
            else         ((float*)Cout)[oidx] = v;
        }
    }
}

// ---------------------------------------------------------------------------
// bf16 MFMA GEMM for logits: C = A(M x K bf16) @ Bt^T + bias, Bt is N x K bf16
// row-major. Emits to out[(b*T + t)*V + n] with finished-mask. m97 structure:
// 128x128 tile, BK=32, 4 waves in 2x2, 16x16x32 MFMA, global_load_lds x16.
// ---------------------------------------------------------------------------
__global__ __launch_bounds__(256) void gemm_mfma_logits(
        const unsigned short* __restrict__ A,   // M x 512
        const unsigned short* __restrict__ Bt,  // N x 512
        const float* __restrict__ bias,
        float* __restrict__ out,
        int M, const int* __restrict__ lens) {
    __shared__ __align__(16) unsigned short As[128 * 32];
    __shared__ __align__(16) unsigned short Bs[128 * 32];

    const int K = 512, N = V_;
    int bm = blockIdx.y * 128;
    int bn = blockIdx.x * 128;
    int tid = threadIdx.x;
    int wave = tid >> 6, lane = tid & 63;

    int wm = (wave & 1) * 64;   // wave tile row
    int wn = (wave >> 1) * 64;  // wave tile col

    f32x4 acc[4][4];
#pragma unroll
    for (int i = 0; i < 4; i++)
#pragma unroll
        for (int j = 0; j < 4; j++) acc[i][j] = (f32x4){0.f, 0.f, 0.f, 0.f};

    // staging address pieces: per round p (0/1), lane covers
    // row = p*64 + wave*16 + (lane>>2), k-seg = (lane&3)*8 elements
    int srow = wave * 16 + (lane >> 2);
    int skoff = (lane & 3) * 8;

    for (int k0 = 0; k0 < K; k0 += 32) {
#pragma unroll
        for (int p = 0; p < 2; p++) {
            int r = p * 64 + srow;
            int ar = bm + r; if (ar > M - 1) ar = M - 1;
            gload_lds16(A + (size_t)ar * K + k0 + skoff,
                        (void*)(As + (size_t)(p * 64 + wave * 16) * 32 ));
            gload_lds16(Bt + (size_t)(bn + r) * K + k0 + skoff,
                        (void*)(Bs + (size_t)(p * 64 + wave * 16) * 32 ));
        }
        __syncthreads();

        int mrow = wm + (lane & 15);
        int nrow = wn + (lane & 15);
        int kq = (lane >> 4) * 8;
        short8 af[4], bf[4];
#pragma unroll
        for (int i = 0; i < 4; i++)
            af[i] = *(const short8*)&As[(mrow + i * 16) * 32 + kq];
#pragma unroll
        for (int j = 0; j < 4; j++)
            bf[j] = *(const short8*)&Bs[(nrow + j * 16) * 32 + kq];
#pragma unroll
        for (int i = 0; i < 4; i++)
#pragma unroll
            for (int j = 0; j < 4; j++)
                acc[i][j] = __builtin_amdgcn_mfma_f32_16x16x32_bf16(
                    af[i], bf[j], acc[i][j], 0, 0, 0);
        __syncthreads();
    }

    // C/D layout: col = lane&15, row = (lane>>4)*4 + r   [m89/m91]
    int lcol = lane & 15, lquad = lane >> 4;
#pragma unroll
    for (int i = 0; i < 4; i++) {
#pragma unroll
        for (int r = 0; r < 4; r++) {
            int gr = bm + wm + i * 16 + lquad * 4 + r;
            if (gr >= M) continue;
            int t = gr >> 5, bb = gr & 31;
            bool fin = (t > 0) && ((t - 1) >= lens[bb]);
            size_t obase = ((size_t)bb * T_ + t) * (size_t)V_;
#pragma unroll
            for (int j = 0; j < 4; j++) {
                int gc = bn + wn + j * 16 + lcol;
                float v = fin ? 0.f : (acc[i][j][r] + bias[gc]);
                out[obase + gc] = v;
            }
        }
    }
}

// ---------------------------------------------------------------------------
// LSTM step: z = Zx[t] + h_prev @ Wh  (Wht = Wh^T precomputed, [2048][512])
// grid 128 blocks (each: 4 j-values x 4 gates = 16 cols, all 32 b),
// 256 threads = (bt:4 waves) x (ct:4 gates) x (s:16-way split-K)
// ---------------------------------------------------------------------------
__global__ __launch_bounds__(256) void lstm_step2(
        const float* __restrict__ Zx, const float* __restrict__ Wht,
        const int* __restrict__ lens,
        float* __restrict__ h_all, float* __restrict__ c_all,
        float* __restrict__ ao_concat, int t) {
    __shared__ float Wl[16 * 516];   // 16 cols x 512 k, stride 516 (pad)
    __shared__ float zb[32 * 20];    // z[b][16 cols], stride 20

    int tid = threadIdx.x;
    int j0 = blockIdx.x * 4;
    const float* h_prev = h_all + (size_t)t * B_ * H_;

    // stage 16 weight columns: col c -> gate (c>>2), j = j0 + (c&3)
    {
        int c = tid >> 4, s = tid & 15;
        int col = (c >> 2) * H_ + j0 + (c & 3);
        const float* src = Wht + (size_t)col * H_ + s * 32;
        float* dstp = Wl + c * 516 + s * 32;
#pragma unroll
        for (int i = 0; i < 8; i++)
            *(f32x4*)(dstp + i * 4) = *(const f32x4*)(src + i * 4);
    }
    __syncthreads();

    int bt = tid >> 6;          // wave: 8 b's starting bt*8
    int ct = (tid >> 4) & 3;    // gate
    int s  = tid & 15;          // split-K lane

    float acc[8][4];
#pragma unroll
    for (int bi = 0; bi < 8; bi++)
#pragma unroll
        for (int cc = 0; cc < 4; cc++) acc[bi][cc] = 0.f;

#pragma unroll
    for (int q = 0; q < 8; q++) {
        int kbase = q * 64 + s * 4;
        f32x4 w4[4];
#pragma unroll
        for (int cc = 0; cc < 4; cc++)
            w4[cc] = *(const f32x4*)&Wl[(ct * 4 + cc) * 516 + kbase];
        f32x4 h4[8];
#pragma unroll
        for (int bi = 0; bi < 8; bi++)
            h4[bi] = *(const f32x4*)&h_prev[(size_t)(bt * 8 + bi) * H_ + kbase];
#pragma unroll
        for (int bi = 0; bi < 8; bi++)
#pragma unroll
            for (int cc = 0; cc < 4; cc++)
                acc[bi][cc] += h4[bi].x * w4[cc].x + h4[bi].y * w4[cc].y +
                               h4[bi].z * w4[cc].z + h4[bi].w * w4[cc].w;
    }

    // reduce across s (low 4 bits of lane)
#pragma unroll
    for (int off = 8; off >= 1; off >>= 1)
#pragma unroll
        for (int bi = 0; bi < 8; bi++)
#pragma unroll
            for (int cc = 0; cc < 4; cc++)
                acc[bi][cc] += __shfl_down(acc[bi][cc], off);

    if (s == 0) {
#pragma unroll
        for (int bi = 0; bi < 8; bi++) {
            int b = bt * 8 + bi;
            f32x4 zx = *(const f32x4*)&Zx[((size_t)t * B_ + b) * (4 * H_) + ct * H_ + j0];
            f32x4 v;
            v.x = acc[bi][0] + zx.x; v.y = acc[bi][1] + zx.y;
            v.z = acc[bi][2] + zx.z; v.w = acc[bi][3] + zx.w;
            *(f32x4*)&zb[b * 20 + ct * 4] = v;
        }
    }
    __syncthreads();

    if (tid < 128) {
        int b = tid >> 2, cj = tid & 3;
        int j = j0 + cj;
        float zi = zb[b * 20 + 0 + cj];
        float zj = zb[b * 20 + 4 + cj];
        float zf = zb[b * 20 + 8 + cj];
        float zo = zb[b * 20 + 12 + cj];
        float cp = c_all[(size_t)t * B_ * H_ + (size_t)b * H_ + j];
        float hp = h_prev[(size_t)b * H_ + j];
        float c = sigmoidf_(zf + 1.0f) * cp + sigmoidf_(zi) * tanhf(zj);
        float h = sigmoidf_(zo) * tanhf(c);
        bool fin = (t > 0) && ((t - 1) >= lens[b]);
        h_all[(size_t)(t + 1) * B_ * H_ + (size_t)b * H_ + j] = fin ? hp : h;
        c_all[(size_t)(t + 1) * B_ * H_ + (size_t)b * H_ + j] = fin ? cp : c;
        ao_concat[((size_t)t * B_ + b) * 1024 + 512 + j] = fin ? 0.f : h;
    }
}

// ---------------------------------------------------------------------------
__global__ void attention_kernel(const float* __restrict__ phi_hs,
                                 const float* __restrict__ phi_fds,
                                 const float* __restrict__ gamma,
                                 const float* __restrict__ alpha,
                                 const float* __restrict__ enc,
                                 float* __restrict__ ao_concat) {
    int r = blockIdx.x;
    int b = r % B_;
    int tid = threadIdx.x;
    __shared__ float gs[H_], asd[H_];
    __shared__ float sh[LS_], sf[LS_];
    for (int k = tid; k < H_; k += 256) {
        gs[k] = gamma[(size_t)r * H_ + k];
        asd[k] = alpha[(size_t)r * H_ + k];
    }
    __syncthreads();
    int wave = tid >> 6, lane = tid & 63;
    for (int l = wave; l < LS_; l += 4) {
        const float* ph = phi_hs + ((size_t)b * LS_ + l) * H_;
        const float* pf = phi_fds + ((size_t)b * LS_ + l) * H_;
        float s1 = 0.f, s2 = 0.f;
        for (int k = lane; k < H_; k += 64) { s1 += ph[k] * gs[k]; s2 += pf[k] * asd[k]; }
#pragma unroll
        for (int off = 32; off; off >>= 1) {
            s1 += __shfl_down(s1, off);
            s2 += __shfl_down(s2, off);
        }
        if (lane == 0) { sh[l] = s1; sf[l] = s2; }
    }
    __syncthreads();
    if (tid == 0) {
        float m1 = -1e30f, m2 = -1e30f;
        for (int l = 0; l < LS_; l++) { m1 = fmaxf(m1, sh[l]); m2 = fmaxf(m2, sf[l]); }
        float s1 = 0.f, s2 = 0.f;
        for (int l = 0; l < LS_; l++) {
            float e1 = expf(sh[l] - m1); sh[l] = e1; s1 += e1;
            float e2 = expf(sf[l] - m2); sf[l] = e2; s2 += e2;
        }
        float r1 = 1.f / (EPS_ + s1), r2 = 1.f / (EPS_ + s2);
        float s3 = 0.f;
        for (int l = 0; l < LS_; l++) { float w = (sh[l] * r1) * (sf[l] * r2); sh[l] = w; s3 += w; }
        float r3 = 1.f / (EPS_ + s3);
        for (int l = 0; l < LS_; l++) sh[l] *= r3;
    }
    __syncthreads();
    for (int h = tid; h < H_; h += 256) {
        float acc = 0.f;
        const float* eb = enc + (size_t)b * LS_ * H_ + h;
        for (int l = 0; l < LS_; l++) acc += sh[l] * eb[(size_t)l * H_];
        ao_concat[(size_t)r * 1024 + h] = acc;
    }
}

__global__ void write_final(const float* __restrict__ h_all, const float* __restrict__ c_all,
                            float* __restrict__ out) {
    int idx = blockIdx.x * blockDim.x + threadIdx.x;
    if (idx < B_ * H_) {
        size_t base = (size_t)B_ * T_ * V_;
        out[base + idx] = h_all[(size_t)T_ * B_ * H_ + idx];
        out[base + B_ * H_ + idx] = c_all[(size_t)T_ * B_ * H_ + idx];
    }
}

extern "C" void kernel_launch(void* const* d_in, const int* in_sizes, int n_in,
                              void* d_out, int out_size, void* d_ws, size_t ws_size,
                              hipStream_t stream) {
    const float* h0   = (const float*)d_in[0];
    const float* c0   = (const float*)d_in[1];
    const float* inp_emb = (const float*)d_in[2];
    const float* enc  = (const float*)d_in[3];
    const float* fld  = (const float*)d_in[4];
    const float* emb  = (const float*)d_in[5];
    const float* lstm_W = (const float*)d_in[6];
    const float* lstm_b = (const float*)d_in[7];
    const float* Wh = (const float*)d_in[8];
    const float* bh = (const float*)d_in[9];
    const float* Ws = (const float*)d_in[10];
    const float* bs = (const float*)d_in[11];
    const float* Wr = (const float*)d_in[12];
    const float* br = (const float*)d_in[13];
    const float* Wf = (const float*)d_in[14];
    const float* bf = (const float*)d_in[15];
    const float* Wo = (const float*)d_in[16];
    const float* bo = (const float*)d_in[17];
    const float* out_W = (const float*)d_in[18];
    const float* out_b = (const float*)d_in[19];
    const int*   lens  = (const int*)d_in[20];
    float* out = (float*)d_out;

    float* ws = (float*)d_ws;
    float* X       = ws; ws += (size_t)T_ * B_ * E_;        // 2080x512
    float* Zx      = ws; ws += (size_t)T_ * B_ * 4 * H_;    // 2080x2048
    float* phi_hs  = ws; ws += (size_t)B_ * LS_ * H_;       // 3200x512
    float* phi_fds = ws; ws += (size_t)B_ * LS_ * H_;       // 3200x512
    float* h_all   = ws; ws += (size_t)(T_ + 1) * B_ * H_;
    float* c_all   = ws; ws += (size_t)(T_ + 1) * B_ * H_;
    float* ao      = ws; ws += (size_t)T_ * B_ * 1024;      // [context|o_t]
    float* gamma   = ws; ws += (size_t)T_ * B_ * H_;
    float* alpha   = ws; ws += (size_t)T_ * B_ * H_;
    float* Wht     = ws; ws += (size_t)4 * H_ * H_;         // 2048x512
    unsigned short* att_bf = (unsigned short*)ws; ws += ((size_t)T_ * B_ * H_ + 1) / 2;
    // Wt_bf (32000x512 bf16 = 32.8 MB) aliases X+Zx+phi_hs+phi_fds (34.4 MB),
    // all dead by the time the transpose runs (after attention_kernel).
    unsigned short* Wt_bf = (unsigned short*)X;

    build_X<<<(T_ * B_ * E_ + 255) / 256, 256, 0, stream>>>(emb, inp_emb, X);
    init_state<<<(B_ * H_ + 255) / 256, 256, 0, stream>>>(h0, c0, h_all, c_all);
    // Wht[c][k] = lstm_W[E+k][c]
    {
        dim3 g(4 * H_ / 32, H_ / 32);
        transpose_f32<<<g, 256, 0, stream>>>(lstm_W + (size_t)E_ * 4 * H_, Wht, H_, 4 * H_);
    }
    // Zx = X @ lstm_W[:E,:] + lstm_b
    {
        dim3 g(2048 / 64, (T_ * B_ + 63) / 64);
        gemm_f32<64, 64, 16, 4, 4, false, false, false><<<g, 256, 0, stream>>>(
            X, lstm_W, lstm_b, Zx, T_ * B_, 2048, 512, 512, nullptr);
    }
    // phi_hs / phi_fds
    {
        dim3 g(512 / 64, 3200 / 64);
        gemm_f32<64, 64, 16, 4, 4, true, false, false><<<g, 256, 0, stream>>>(
            enc, Wh, bh, phi_hs, B_ * LS_, 512, 512, 512, nullptr);
        gemm_f32<64, 64, 16, 4, 4, true, false, false><<<g, 256, 0, stream>>>(
            fld, Wf, bf, phi_fds, B_ * LS_, 512, 64, 64, nullptr);
    }
    // sequential LSTM chain
    for (int t = 0; t < T_; t++) {
        lstm_step2<<<128, 256, 0, stream>>>(Zx, Wht, lens, h_all, c_all, ao, t);
    }
    // gamma / alpha
    {
        dim3 g(512 / 64, (T_ * B_ + 63) / 64);
        gemm_f32<64, 64, 16, 4, 4, true, false, false><<<g, 256, 0, stream>>>(
            ao + 512, Ws, bs, gamma, T_ * B_, 512, 512, 1024, nullptr);
        gemm_f32<64, 64, 16, 4, 4, true, false, false><<<g, 256, 0, stream>>>(
            ao + 512, Wr, br, alpha, T_ * B_, 512, 512, 1024, nullptr);
    }
    attention_kernel<<<T_ * B_, 256, 0, stream>>>(phi_hs, phi_fds, gamma, alpha, enc, ao);
    // att (bf16) = tanh([context|o_t] @ Wo + bo), masked
    {
        dim3 g(512 / 64, (T_ * B_ + 63) / 64);
        gemm_f32<64, 64, 16, 4, 4, true, true, true><<<g, 256, 0, stream>>>(
            ao, Wo, bo, att_bf, T_ * B_, 512, 1024, 1024, lens);
    }
    // Wt_bf[n][k] = bf16(out_W[k][n])  (phi/X/Zx dead now)
    {
        dim3 g(V_ / 32, 512 / 32);
        transpose_f32_to_bf16<<<g, 256, 0, stream>>>(out_W, Wt_bf, 512, V_);
    }
    // logits = att @ out_W + out_b via bf16 MFMA, masked, emit scatter
    {
        dim3 g(V_ / 128, (T_ * B_ + 127) / 128);
        gemm_mfma_logits<<<g, 256, 0, stream>>>(att_bf, Wt_bf, out_b, out, T_ * B_, lens);
    }
    write_final<<<(B_ * H_ + 255) / 256, 256, 0, stream>>>(h_all, c_all, out);
}

// Round 3
// 1421.945 us; speedup vs baseline: 2.5936x; 1.3842x over previous
//
#include <hip/hip_runtime.h>
#include <math.h>

#define B_ 32
#define L_ 64
#define T_ 65      // 1 + L
#define LS_ 100
#define H_ 512
#define E_ 512
#define F_ 64
#define V_ 32000
#define SOS_ 2
#define EPS_ 1e-6f

typedef __attribute__((ext_vector_type(8))) _Float16 half8;
typedef __attribute__((ext_vector_type(4))) float f32x4;

__device__ __forceinline__ float sigmoidf_(float x) { return 1.0f / (1.0f + expf(-x)); }

__device__ __forceinline__ void gload_lds16(const void* g, void* l) {
    __builtin_amdgcn_global_load_lds(
        (const __attribute__((address_space(1))) unsigned int*)g,
        (__attribute__((address_space(3))) unsigned int*)l, 16, 0, 0);
}

// ---------------------------------------------------------------------------
__global__ void build_X(const float* __restrict__ emb,
                        const float* __restrict__ inp_emb,
                        _Float16* __restrict__ X) {
    int idx = blockIdx.x * blockDim.x + threadIdx.x;
    if (idx >= T_ * B_ * E_) return;
    int e = idx % E_;
    int r = idx / E_;
    int t = r / B_, b = r % B_;
    float v;
    if (t == 0) v = emb[(size_t)SOS_ * E_ + e];
    else        v = inp_emb[((size_t)b * L_ + (t - 1)) * E_ + e];
    X[idx] = (_Float16)v;
}

__global__ void init_state(const float* __restrict__ h0, const float* __restrict__ c0,
                           float* __restrict__ h_all, float* __restrict__ c_all) {
    int idx = blockIdx.x * blockDim.x + threadIdx.x;
    if (idx < B_ * H_) { h_all[idx] = h0[idx]; c_all[idx] = c0[idx]; }
}

__global__ void convert_f16(const float* __restrict__ src, _Float16* __restrict__ dst, int n) {
    int idx = blockIdx.x * blockDim.x + threadIdx.x;
    if (idx < n) dst[idx] = (_Float16)src[idx];
}

__global__ void build_bsr(const float* __restrict__ bs, const float* __restrict__ br,
                          float* __restrict__ bsr) {
    int idx = blockIdx.x * blockDim.x + threadIdx.x;
    if (idx < H_) { bsr[idx] = bs[idx]; bsr[H_ + idx] = br[idx]; }
}

// ---------------------------------------------------------------------------
// Tiled transposes: dst[c][r] = src[r][c], src R x C row-major (R,C mult of 32)
// ---------------------------------------------------------------------------
__global__ void transpose_f32(const float* __restrict__ src, float* __restrict__ dst,
                              int R, int C) {
    __shared__ float tl[32][33];
    int r0 = blockIdx.y * 32, c0 = blockIdx.x * 32;
    int cx = threadIdx.x & 31, g = threadIdx.x >> 5;
#pragma unroll
    for (int i = 0; i < 4; i++) {
        int ry = g * 4 + i;
        tl[ry][cx] = src[(size_t)(r0 + ry) * C + c0 + cx];
    }
    __syncthreads();
#pragma unroll
    for (int i = 0; i < 4; i++) {
        int cy = g * 4 + i;
        dst[(size_t)(c0 + cy) * R + r0 + cx] = tl[cx][cy];
    }
}

__global__ void transpose_f32_to_f16(const float* __restrict__ src,
                                     _Float16* __restrict__ dst, int R, int C) {
    __shared__ float tl[32][33];
    int r0 = blockIdx.y * 32, c0 = blockIdx.x * 32;
    int cx = threadIdx.x & 31, g = threadIdx.x >> 5;
#pragma unroll
    for (int i = 0; i < 4; i++) {
        int ry = g * 4 + i;
        tl[ry][cx] = src[(size_t)(r0 + ry) * C + c0 + cx];
    }
    __syncthreads();
#pragma unroll
    for (int i = 0; i < 4; i++) {
        int cy = g * 4 + i;
        dst[(size_t)(c0 + cy) * R + r0 + cx] = (_Float16)tl[cx][cy];
    }
}

// ---------------------------------------------------------------------------
// Unified f16 MFMA GEMM (m97 structure): C = act(A[M x K](lda) @ Bt^T + bias)
// Bt is N x K row-major f16. 128x128 tile, BK=32, 4 waves 2x2, 16x16x32 MFMA,
// global_load_lds width 16. EMIT: scatter to out[(b*T+t)*V + n].
// ---------------------------------------------------------------------------
template <bool TANH, bool MASK, bool OUTF16, bool EMIT>
__global__ __launch_bounds__(256) void gemm_mfma(
        const _Float16* __restrict__ A, int lda,
        const _Float16* __restrict__ Bt,
        const float* __restrict__ bias, void* __restrict__ Cout,
        int M, int N, int K, const int* __restrict__ lens) {
    __shared__ __align__(16) _Float16 As[128 * 32];
    __shared__ __align__(16) _Float16 Bs[128 * 32];

    int bm = blockIdx.y * 128;
    int bn = blockIdx.x * 128;
    int tid = threadIdx.x;
    int wave = tid >> 6, lane = tid & 63;

    int wm = (wave & 1) * 64;
    int wn = (wave >> 1) * 64;

    f32x4 acc[4][4];
#pragma unroll
    for (int i = 0; i < 4; i++)
#pragma unroll
        for (int j = 0; j < 4; j++) acc[i][j] = (f32x4){0.f, 0.f, 0.f, 0.f};

    int srow = wave * 16 + (lane >> 2);
    int skoff = (lane & 3) * 8;

    for (int k0 = 0; k0 < K; k0 += 32) {
#pragma unroll
        for (int p = 0; p < 2; p++) {
            int r = p * 64 + srow;
            int ar = bm + r; if (ar > M - 1) ar = M - 1;
            gload_lds16(A + (size_t)ar * lda + k0 + skoff,
                        (void*)(As + (size_t)(p * 64 + wave * 16) * 32));
            gload_lds16(Bt + (size_t)(bn + r) * K + k0 + skoff,
                        (void*)(Bs + (size_t)(p * 64 + wave * 16) * 32));
        }
        __syncthreads();

        int mrow = wm + (lane & 15);
        int nrow = wn + (lane & 15);
        int kq = (lane >> 4) * 8;
        half8 afr[4], bfr[4];
#pragma unroll
        for (int i = 0; i < 4; i++)
            afr[i] = *(const half8*)&As[(mrow + i * 16) * 32 + kq];
#pragma unroll
        for (int j = 0; j < 4; j++)
            bfr[j] = *(const half8*)&Bs[(nrow + j * 16) * 32 + kq];
#pragma unroll
        for (int i = 0; i < 4; i++)
#pragma unroll
            for (int j = 0; j < 4; j++)
                acc[i][j] = __builtin_amdgcn_mfma_f32_16x16x32_f16(
                    afr[i], bfr[j], acc[i][j], 0, 0, 0);
        __syncthreads();
    }

    // C/D layout: col = lane&15, row = (lane>>4)*4 + r   [m89/m91]
    int lcol = lane & 15, lquad = lane >> 4;
#pragma unroll
    for (int i = 0; i < 4; i++) {
#pragma unroll
        for (int r = 0; r < 4; r++) {
            int gr = bm + wm + i * 16 + lquad * 4 + r;
            if (gr >= M) continue;
            bool fin = false;
            int t = gr >> 5, bb = gr & 31;
            if (MASK) fin = (t > 0) && ((t - 1) >= lens[bb]);
#pragma unroll
            for (int j = 0; j < 4; j++) {
                int gc = bn + wn + j * 16 + lcol;
                float v = acc[i][j][r] + bias[gc];
                if (TANH) v = tanhf(v);
                if (MASK && fin) v = 0.f;
                if (EMIT) {
                    ((float*)Cout)[((size_t)bb * T_ + t) * (size_t)V_ + gc] = v;
                } else if (OUTF16) {
                    ((_Float16*)Cout)[(size_t)gr * N + gc] = (_Float16)v;
                } else {
                    ((float*)Cout)[(size_t)gr * N + gc] = v;
                }
            }
        }
    }
}

// ---------------------------------------------------------------------------
// LSTM step: z = Zx[t] + h_prev @ Wh  (Wht = Wh^T precomputed f32 [2048][512])
// ---------------------------------------------------------------------------
__global__ __launch_bounds__(256) void lstm_step2(
        const float* __restrict__ Zx, const float* __restrict__ Wht,
        const int* __restrict__ lens,
        float* __restrict__ h_all, float* __restrict__ c_all,
        _Float16* __restrict__ ao_concat, int t) {
    __shared__ float Wl[16 * 516];
    __shared__ float zb[32 * 20];

    int tid = threadIdx.x;
    int j0 = blockIdx.x * 4;
    const float* h_prev = h_all + (size_t)t * B_ * H_;

    {
        int c = tid >> 4, s = tid & 15;
        int col = (c >> 2) * H_ + j0 + (c & 3);
        const float* src = Wht + (size_t)col * H_ + s * 32;
        float* dstp = Wl + c * 516 + s * 32;
#pragma unroll
        for (int i = 0; i < 8; i++)
            *(f32x4*)(dstp + i * 4) = *(const f32x4*)(src + i * 4);
    }
    __syncthreads();

    int bt = tid >> 6;
    int ct = (tid >> 4) & 3;
    int s  = tid & 15;

    float acc[8][4];
#pragma unroll
    for (int bi = 0; bi < 8; bi++)
#pragma unroll
        for (int cc = 0; cc < 4; cc++) acc[bi][cc] = 0.f;

#pragma unroll
    for (int q = 0; q < 8; q++) {
        int kbase = q * 64 + s * 4;
        f32x4 w4[4];
#pragma unroll
        for (int cc = 0; cc < 4; cc++)
            w4[cc] = *(const f32x4*)&Wl[(ct * 4 + cc) * 516 + kbase];
        f32x4 h4[8];
#pragma unroll
        for (int bi = 0; bi < 8; bi++)
            h4[bi] = *(const f32x4*)&h_prev[(size_t)(bt * 8 + bi) * H_ + kbase];
#pragma unroll
        for (int bi = 0; bi < 8; bi++)
#pragma unroll
            for (int cc = 0; cc < 4; cc++)
                acc[bi][cc] += h4[bi].x * w4[cc].x + h4[bi].y * w4[cc].y +
                               h4[bi].z * w4[cc].z + h4[bi].w * w4[cc].w;
    }

#pragma unroll
    for (int off = 8; off >= 1; off >>= 1)
#pragma unroll
        for (int bi = 0; bi < 8; bi++)
#pragma unroll
            for (int cc = 0; cc < 4; cc++)
                acc[bi][cc] += __shfl_down(acc[bi][cc], off);

    if (s == 0) {
#pragma unroll
        for (int bi = 0; bi < 8; bi++) {
            int b = bt * 8 + bi;
            f32x4 zx = *(const f32x4*)&Zx[((size_t)t * B_ + b) * (4 * H_) + ct * H_ + j0];
            f32x4 v;
            v.x = acc[bi][0] + zx.x; v.y = acc[bi][1] + zx.y;
            v.z = acc[bi][2] + zx.z; v.w = acc[bi][3] + zx.w;
            *(f32x4*)&zb[b * 20 + ct * 4] = v;
        }
    }
    __syncthreads();

    if (tid < 128) {
        int b = tid >> 2, cj = tid & 3;
        int j = j0 + cj;
        float zi = zb[b * 20 + 0 + cj];
        float zj = zb[b * 20 + 4 + cj];
        float zf = zb[b * 20 + 8 + cj];
        float zo = zb[b * 20 + 12 + cj];
        float cp = c_all[(size_t)t * B_ * H_ + (size_t)b * H_ + j];
        float hp = h_prev[(size_t)b * H_ + j];
        float c = sigmoidf_(zf + 1.0f) * cp + sigmoidf_(zi) * tanhf(zj);
        float h = sigmoidf_(zo) * tanhf(c);
        bool fin = (t > 0) && ((t - 1) >= lens[b]);
        h_all[(size_t)(t + 1) * B_ * H_ + (size_t)b * H_ + j] = fin ? hp : h;
        c_all[(size_t)(t + 1) * B_ * H_ + (size_t)b * H_ + j] = fin ? cp : c;
        ao_concat[((size_t)t * B_ + b) * 1024 + 512 + j] = (_Float16)(fin ? 0.f : h);
    }
}

// ---------------------------------------------------------------------------
__global__ void attention_kernel(const _Float16* __restrict__ phi_hs,
                                 const _Float16* __restrict__ phi_fds,
                                 const float* __restrict__ ga,
                                 const float* __restrict__ enc,
                                 _Float16* __restrict__ ao_concat) {
    int r = blockIdx.x;
    int b = r % B_;
    int tid = threadIdx.x;
    __shared__ float gs[H_], asd[H_];
    __shared__ float sh[LS_], sf[LS_];
    for (int k = tid; k < H_; k += 256) {
        gs[k]  = ga[(size_t)r * 1024 + k];
        asd[k] = ga[(size_t)r * 1024 + 512 + k];
    }
    __syncthreads();
    int wave = tid >> 6, lane = tid & 63;
    for (int l = wave; l < LS_; l += 4) {
        const _Float16* ph = phi_hs + ((size_t)b * LS_ + l) * H_;
        const _Float16* pf = phi_fds + ((size_t)b * LS_ + l) * H_;
        float s1 = 0.f, s2 = 0.f;
        for (int k = lane; k < H_; k += 64) {
            s1 += (float)ph[k] * gs[k];
            s2 += (float)pf[k] * asd[k];
        }
#pragma unroll
        for (int off = 32; off; off >>= 1) {
            s1 += __shfl_down(s1, off);
            s2 += __shfl_down(s2, off);
        }
        if (lane == 0) { sh[l] = s1; sf[l] = s2; }
    }
    __syncthreads();
    if (tid == 0) {
        float m1 = -1e30f, m2 = -1e30f;
        for (int l = 0; l < LS_; l++) { m1 = fmaxf(m1, sh[l]); m2 = fmaxf(m2, sf[l]); }
        float s1 = 0.f, s2 = 0.f;
        for (int l = 0; l < LS_; l++) {
            float e1 = expf(sh[l] - m1); sh[l] = e1; s1 += e1;
            float e2 = expf(sf[l] - m2); sf[l] = e2; s2 += e2;
        }
        float r1 = 1.f / (EPS_ + s1), r2 = 1.f / (EPS_ + s2);
        float s3 = 0.f;
        for (int l = 0; l < LS_; l++) { float w = (sh[l] * r1) * (sf[l] * r2); sh[l] = w; s3 += w; }
        float r3 = 1.f / (EPS_ + s3);
        for (int l = 0; l < LS_; l++) sh[l] *= r3;
    }
    __syncthreads();
    for (int h = tid; h < H_; h += 256) {
        float acc = 0.f;
        const float* eb = enc + (size_t)b * LS_ * H_ + h;
        for (int l = 0; l < LS_; l++) acc += sh[l] * eb[(size_t)l * H_];
        ao_concat[(size_t)r * 1024 + h] = (_Float16)acc;
    }
}

__global__ void write_final(const float* __restrict__ h_all, const float* __restrict__ c_all,
                            float* __restrict__ out) {
    int idx = blockIdx.x * blockDim.x + threadIdx.x;
    if (idx < B_ * H_) {
        size_t base = (size_t)B_ * T_ * V_;
        out[base + idx] = h_all[(size_t)T_ * B_ * H_ + idx];
        out[base + B_ * H_ + idx] = c_all[(size_t)T_ * B_ * H_ + idx];
    }
}

extern "C" void kernel_launch(void* const* d_in, const int* in_sizes, int n_in,
                              void* d_out, int out_size, void* d_ws, size_t ws_size,
                              hipStream_t stream) {
    const float* h0   = (const float*)d_in[0];
    const float* c0   = (const float*)d_in[1];
    const float* inp_emb = (const float*)d_in[2];
    const float* enc  = (const float*)d_in[3];
    const float* fld  = (const float*)d_in[4];
    const float* emb  = (const float*)d_in[5];
    const float* lstm_W = (const float*)d_in[6];
    const float* lstm_b = (const float*)d_in[7];
    const float* Wh = (const float*)d_in[8];
    const float* bh = (const float*)d_in[9];
    const float* Ws = (const float*)d_in[10];
    const float* bs = (const float*)d_in[11];
    const float* Wr = (const float*)d_in[12];
    const float* br = (const float*)d_in[13];
    const float* Wf = (const float*)d_in[14];
    const float* bfp = (const float*)d_in[15];
    const float* Wo = (const float*)d_in[16];
    const float* bo = (const float*)d_in[17];
    const float* out_W = (const float*)d_in[18];
    const float* out_b = (const float*)d_in[19];
    const int*   lens  = (const int*)d_in[20];
    float* out = (float*)d_out;

    char* p = (char*)d_ws;
    auto alloc = [&](size_t bytes) { char* r = p; p += (bytes + 255) & ~(size_t)255; return r; };

    // --- alias region (all dead before out_W transpose) ---
    char* region = p;
    float*    Zx    = (float*)   alloc((size_t)T_ * B_ * 4 * H_ * 4);  // 17.04 MB
    float*    ga    = (float*)   alloc((size_t)T_ * B_ * 1024 * 4);    //  8.52 MB
    _Float16* X_h   = (_Float16*)alloc((size_t)T_ * B_ * E_ * 2);      //  2.13 MB
    _Float16* enc_h = (_Float16*)alloc((size_t)B_ * LS_ * H_ * 2);     //  3.28 MB
    _Float16* Wxt_h = (_Float16*)alloc((size_t)4 * H_ * E_ * 2);       //  2.10 MB
    _Float16* Wt_h  = (_Float16*)region;  // 32000x512 f16 = 32.77 MB <= 33.07 MB
    // --- persistent ---
    _Float16* phi_hs_h  = (_Float16*)alloc((size_t)B_ * LS_ * H_ * 2);
    _Float16* phi_fds_h = (_Float16*)alloc((size_t)B_ * LS_ * H_ * 2);
    float*    h_all = (float*)alloc((size_t)(T_ + 1) * B_ * H_ * 4);
    float*    c_all = (float*)alloc((size_t)(T_ + 1) * B_ * H_ * 4);
    _Float16* ao_h  = (_Float16*)alloc((size_t)T_ * B_ * 1024 * 2);
    float*    Wht   = (float*)alloc((size_t)4 * H_ * H_ * 4);
    _Float16* fld_h = (_Float16*)alloc((size_t)B_ * LS_ * F_ * 2);
    _Float16* Wh_t  = (_Float16*)alloc((size_t)H_ * H_ * 2);
    _Float16* Wsr_t = (_Float16*)alloc((size_t)1024 * H_ * 2);
    _Float16* Wo_t  = (_Float16*)alloc((size_t)H_ * 1024 * 2);
    _Float16* Wf_t  = (_Float16*)alloc((size_t)H_ * F_ * 2);
    _Float16* att_h = (_Float16*)alloc((size_t)T_ * B_ * H_ * 2);
    float*    bsr   = (float*)alloc(1024 * 4);

    // ---- setup / conversions ----
    build_X<<<(T_ * B_ * E_ + 255) / 256, 256, 0, stream>>>(emb, inp_emb, X_h);
    init_state<<<(B_ * H_ + 255) / 256, 256, 0, stream>>>(h0, c0, h_all, c_all);
    build_bsr<<<2, 256, 0, stream>>>(bs, br, bsr);
    convert_f16<<<(B_ * LS_ * H_ + 255) / 256, 256, 0, stream>>>(enc, enc_h, B_ * LS_ * H_);
    convert_f16<<<(B_ * LS_ * F_ + 255) / 256, 256, 0, stream>>>(fld, fld_h, B_ * LS_ * F_);
    {   // Wht f32 = lstm_W[E:,:]^T ; Wxt_h f16 = lstm_W[:E,:]^T
        dim3 g(4 * H_ / 32, H_ / 32);
        transpose_f32<<<g, 256, 0, stream>>>(lstm_W + (size_t)E_ * 4 * H_, Wht, H_, 4 * H_);
        transpose_f32_to_f16<<<g, 256, 0, stream>>>(lstm_W, Wxt_h, E_, 4 * H_);
    }
    {   dim3 g(H_ / 32, H_ / 32);
        transpose_f32_to_f16<<<g, 256, 0, stream>>>(Wh, Wh_t, H_, H_);
        transpose_f32_to_f16<<<g, 256, 0, stream>>>(Ws, Wsr_t, H_, H_);
        transpose_f32_to_f16<<<g, 256, 0, stream>>>(Wr, Wsr_t + (size_t)H_ * H_, H_, H_);
    }
    {   dim3 g(H_ / 32, F_ / 32);
        transpose_f32_to_f16<<<g, 256, 0, stream>>>(Wf, Wf_t, F_, H_);
    }
    {   dim3 g(H_ / 32, 1024 / 32);
        transpose_f32_to_f16<<<g, 256, 0, stream>>>(Wo, Wo_t, 1024, H_);
    }

    // ---- feedforward GEMMs (f16 MFMA) ----
    // Zx = X @ lstm_W[:E] + lstm_b   (f32 out, needed by recurrence)
    {   dim3 g(2048 / 128, (T_ * B_ + 127) / 128);
        gemm_mfma<false, false, false, false><<<g, 256, 0, stream>>>(
            X_h, E_, Wxt_h, lstm_b, Zx, T_ * B_, 2048, 512, nullptr);
    }
    // phi_hs = tanh(enc @ Wh + bh); phi_fds = tanh(fld @ Wf + bf)
    {   dim3 g(512 / 128, 3200 / 128);
        gemm_mfma<true, false, true, false><<<g, 256, 0, stream>>>(
            enc_h, H_, Wh_t, bh, phi_hs_h, B_ * LS_, 512, 512, nullptr);
        gemm_mfma<true, false, true, false><<<g, 256, 0, stream>>>(
            fld_h, F_, Wf_t, bfp, phi_fds_h, B_ * LS_, 512, 64, nullptr);
    }
    // ---- sequential LSTM chain ----
    for (int t = 0; t < T_; t++) {
        lstm_step2<<<128, 256, 0, stream>>>(Zx, Wht, lens, h_all, c_all, ao_h, t);
    }
    // ga = tanh(o_t @ [Ws|Wr] + [bs|br])   (2080 x 1024 x 512, f32 out)
    {   dim3 g(1024 / 128, (T_ * B_ + 127) / 128);
        gemm_mfma<true, false, false, false><<<g, 256, 0, stream>>>(
            ao_h + 512, 1024, Wsr_t, bsr, ga, T_ * B_, 1024, 512, nullptr);
    }
    attention_kernel<<<T_ * B_, 256, 0, stream>>>(phi_hs_h, phi_fds_h, ga, enc, ao_h);
    // Wt_h = out_W^T f16 (aliases Zx/ga/X_h/enc_h/Wxt_h — all dead now)
    {   dim3 g(V_ / 32, 512 / 32);
        transpose_f32_to_f16<<<g, 256, 0, stream>>>(out_W, Wt_h, 512, V_);
    }
    // att = tanh([context|o_t] @ Wo + bo), masked, f16 out
    {   dim3 g(512 / 128, (T_ * B_ + 127) / 128);
        gemm_mfma<true, true, true, false><<<g, 256, 0, stream>>>(
            ao_h, 1024, Wo_t, bo, att_h, T_ * B_, 512, 1024, lens);
    }
    // logits = att @ out_W + out_b, masked, emit-scatter
    {   dim3 g(V_ / 128, (T_ * B_ + 127) / 128);
        gemm_mfma<false, true, false, true><<<g, 256, 0, stream>>>(
            att_h, H_, Wt_h, out_b, out, T_ * B_, V_, 512, lens);
    }
    write_final<<<(B_ * H_ + 255) / 256, 256, 0, stream>>>(h_all, c_all, out);
}